// Round 4
// baseline (138.334 us; speedup 1.0000x reference)
//
#include <hip/hip_runtime.h>
#include <hip/hip_bf16.h>

// out[b,m,d,f] = sum_{a,c} x[b,m,a,f] * y[b,m,c,f] * cgc[a,d,c]
// MFMA formulation, per bm point: out[16,128] = W[16,256] . P[256,128]
//   k = a*16+c; W[d,k]=cgc[a,d,c] (register-resident A-frags, verified layout)
//   P[k,f] = x[a,f]*y[c,f] built on the fly in bf16.
//
// Round 4 vs round 3 (latency-bound, 4 waves/SIMD, no prefetch):
//  - 2 waves per bm, 4 f-tiles each -> 8192 waves (8/SIMD potential)
//  - prefetch-1 pipeline: next tile's 16 scalar loads issued before current
//    tile's pack+MFMA; tile-0 loads issued before W-frag cvt work.
//  - __launch_bounds__(256,6): VGPR cap ~85, live set ~80.

typedef __attribute__((ext_vector_type(8))) short  short8;
typedef __attribute__((ext_vector_type(4))) float  floatx4;
typedef __attribute__((ext_vector_type(4))) unsigned int uintx4;

#define AA 16
#define FF 128

static __device__ __forceinline__ unsigned int pack_bf16_2(float lo, float hi) {
    __hip_bfloat162 h = __float22bfloat162_rn(make_float2(lo, hi));  // v_cvt_pk_bf16_f32
    unsigned int u;
    __builtin_memcpy(&u, &h, 4);
    return u;
}

__global__ __launch_bounds__(256, 6)
void tpc_mfma2_kernel(const float* __restrict__ x,
                      const float* __restrict__ y,
                      const float* __restrict__ cgc,
                      float* __restrict__ out) {
    const int gwave = (blockIdx.x * 256 + threadIdx.x) >> 6;  // 0..8191
    const int lane  = threadIdx.x & 63;
    const int L     = lane & 15;       // A: m(=d); B: n(=f in tile); D: col
    const int quad  = lane >> 4;
    const int qh    = quad >> 1;       // a parity
    const int c0    = (quad & 1) * 8;  // c sub-range

    const int bm = gwave >> 1;         // 0..4095
    const int t0 = (gwave & 1) * 4;    // this wave's first f-tile (of 8)

    const float* xb = x   + (size_t)bm * (AA * FF);
    const float* yb = y   + (size_t)bm * (AA * FF);
    float*       ob = out + (size_t)bm * (AA * FF);

    // ---- issue tile-0 loads first: their latency overlaps W-frag cvt work ----
    float xv[8], yv[8];
    {
        const int f = t0 * 16 + L;
#pragma unroll
        for (int j = 0; j < 8; ++j) yv[j] = yb[(c0 + j) * FF + f];
#pragma unroll
        for (int t = 0; t < 8; ++t) xv[t] = xb[(2 * t + qh) * FF + f];
    }

    // ---- A fragments (W), register-resident: 8 K-steps x 8 bf16 ----
    short8 wfrag[8];
#pragma unroll
    for (int t = 0; t < 8; ++t) {
        const float* wp = cgc + (2 * t + qh) * (AA * AA) + L * AA + c0;
        const floatx4 w0 = *(const floatx4*)(wp);
        const floatx4 w1 = *(const floatx4*)(wp + 4);
        uintx4 u;
        u.x = pack_bf16_2(w0.x, w0.y);
        u.y = pack_bf16_2(w0.z, w0.w);
        u.z = pack_bf16_2(w1.x, w1.y);
        u.w = pack_bf16_2(w1.z, w1.w);
        wfrag[t] = __builtin_bit_cast(short8, u);
    }

#pragma unroll 1
    for (int it = 0; it < 4; ++it) {
        const int f = (t0 + it) * 16 + L;

        // prefetch next tile (last iter wraps to t0: L1/L2-hot, keeps it branch-free)
        const int fn = (t0 + ((it + 1) & 3)) * 16 + L;
        float xn[8], yn[8];
#pragma unroll
        for (int j = 0; j < 8; ++j) yn[j] = yb[(c0 + j) * FF + fn];
#pragma unroll
        for (int t = 0; t < 8; ++t) xn[t] = xb[(2 * t + qh) * FF + fn];

        floatx4 acc = {0.f, 0.f, 0.f, 0.f};
#pragma unroll
        for (int t = 0; t < 8; ++t) {
            const float xs = xv[t];
            uintx4 u;
            u.x = pack_bf16_2(xs * yv[0], xs * yv[1]);
            u.y = pack_bf16_2(xs * yv[2], xs * yv[3]);
            u.z = pack_bf16_2(xs * yv[4], xs * yv[5]);
            u.w = pack_bf16_2(xs * yv[6], xs * yv[7]);
            const short8 bfrag = __builtin_bit_cast(short8, u);
            acc = __builtin_amdgcn_mfma_f32_16x16x32_bf16(wfrag[t], bfrag, acc, 0, 0, 0);
        }

#pragma unroll
        for (int r = 0; r < 4; ++r)
            ob[(quad * 4 + r) * FF + f] = acc[r];

#pragma unroll
        for (int j = 0; j < 8; ++j) { xv[j] = xn[j]; yv[j] = yn[j]; }
    }
}

extern "C" void kernel_launch(void* const* d_in, const int* in_sizes, int n_in,
                              void* d_out, int out_size, void* d_ws, size_t ws_size,
                              hipStream_t stream) {
    const float* x   = (const float*)d_in[0];
    const float* y   = (const float*)d_in[1];
    const float* cgc = (const float*)d_in[2];
    float* out = (float*)d_out;

    // 4096 bm x 2 waves = 8192 waves -> 2048 blocks x 256 threads
    hipLaunchKernelGGL(tpc_mfma2_kernel, dim3(2048), dim3(256), 0, stream,
                       x, y, cgc, out);
}

// Round 5
// 107.892 us; speedup vs baseline: 1.2821x; 1.2821x over previous
//
#include <hip/hip_runtime.h>
#include <hip/hip_bf16.h>

// out[b,m,d,f] = sum_{a,c} x[b,m,a,f] * y[b,m,c,f] * cgc[a,d,c]
// MFMA per bm: out[16,128] = W[16,256] . P[256,128], k=a*16+c,
//   W[d,k]=cgc[a,d,c] (register A-frags, layout verified in R3/R4, absmax 0.25)
//   P[k,f]=x[a,f]*y[c,f] packed to bf16 on the fly.
//
// Round 5 vs round 4 (over-fetch: FETCH 97MB, WRITE 55MB from 4B loads +
// partial-line stores):
//  - block = 1 bm, 4 waves, 16KB LDS; x,y staged via global_load_lds width=16
//    (coalesced dwordx4, full lines, no VGPR roundtrip)
//  - LDS reads: 2 rows/bank-group = 2-way aliasing (free), broadcasts free
//  - wave w owns adjacent tiles f=32w..32w+31: both 64B halves of every 128B
//    output line stored back-to-back -> no write-allocate RMW
//  - W-frag cvt work overlaps the async staging; one barrier, no loop.

typedef __attribute__((ext_vector_type(8))) short  short8;
typedef __attribute__((ext_vector_type(4))) float  floatx4;
typedef __attribute__((ext_vector_type(4))) unsigned int uintx4;

#define AA 16
#define FF 128

static __device__ __forceinline__ unsigned int pack_bf16_2(float lo, float hi) {
    __hip_bfloat162 h = __float22bfloat162_rn(make_float2(lo, hi));  // v_cvt_pk_bf16_f32
    unsigned int u;
    __builtin_memcpy(&u, &h, 4);
    return u;
}

static __device__ __forceinline__ void gload_lds16(const float* g, float* l) {
    __builtin_amdgcn_global_load_lds(
        (const __attribute__((address_space(1))) void*)g,
        (__attribute__((address_space(3))) void*)l,
        16, 0, 0);
}

__global__ __launch_bounds__(256, 4)
void tpc_mfma_lds_kernel(const float* __restrict__ x,
                         const float* __restrict__ y,
                         const float* __restrict__ cgc,
                         float* __restrict__ out) {
    __shared__ float lx[AA * FF];   // 8KB
    __shared__ float ly[AA * FF];   // 8KB

    const int tid  = threadIdx.x;
    const int w    = tid >> 6;         // wave 0..3
    const int lane = tid & 63;
    const int L    = lane & 15;        // A: m(=d); B: n(=f in tile); D: col
    const int quad = lane >> 4;
    const int qh   = quad >> 1;        // a parity
    const int c0   = (quad & 1) * 8;   // c sub-range

    const int bm = blockIdx.x;         // 0..4095
    const float* xb = x   + (size_t)bm * (AA * FF);
    const float* yb = y   + (size_t)bm * (AA * FF);
    float*       ob = out + (size_t)bm * (AA * FF);

    // ---- async stage x,y -> LDS (each wave: 512 floats of each, 2x16B/lane) ----
    {
        const int off = w * 512 + lane * 4;
        gload_lds16(xb + off,       lx + off);
        gload_lds16(xb + off + 256, lx + off + 256);
        gload_lds16(yb + off,       ly + off);
        gload_lds16(yb + off + 256, ly + off + 256);
    }

    // ---- A fragments (W) from cgc, overlapping the staging latency ----
    short8 wfrag[8];
#pragma unroll
    for (int t = 0; t < 8; ++t) {
        const float* wp = cgc + (2 * t + qh) * (AA * AA) + L * AA + c0;
        const floatx4 w0 = *(const floatx4*)(wp);
        const floatx4 w1 = *(const floatx4*)(wp + 4);
        uintx4 u;
        u.x = pack_bf16_2(w0.x, w0.y);
        u.y = pack_bf16_2(w0.z, w0.w);
        u.z = pack_bf16_2(w1.x, w1.y);
        u.w = pack_bf16_2(w1.z, w1.w);
        wfrag[t] = __builtin_bit_cast(short8, u);
    }

    __syncthreads();   // drains vmcnt (incl. global_load_lds) before LDS reads

    // ---- wave w owns adjacent f-tiles 2w, 2w+1: f0 and f0+16 ----
    const int f0 = w * 32 + L;

    float xvA[8], xvB[8], yvA[8], yvB[8];
#pragma unroll
    for (int j = 0; j < 8; ++j) {
        yvA[j] = ly[(c0 + j) * FF + f0];
        yvB[j] = ly[(c0 + j) * FF + f0 + 16];
    }
#pragma unroll
    for (int t = 0; t < 8; ++t) {
        xvA[t] = lx[(2 * t + qh) * FF + f0];
        xvB[t] = lx[(2 * t + qh) * FF + f0 + 16];
    }

    floatx4 acc0 = {0.f, 0.f, 0.f, 0.f};
    floatx4 acc1 = {0.f, 0.f, 0.f, 0.f};
#pragma unroll
    for (int t = 0; t < 8; ++t) {
        uintx4 u;
        float xs = xvA[t];
        u.x = pack_bf16_2(xs * yvA[0], xs * yvA[1]);
        u.y = pack_bf16_2(xs * yvA[2], xs * yvA[3]);
        u.z = pack_bf16_2(xs * yvA[4], xs * yvA[5]);
        u.w = pack_bf16_2(xs * yvA[6], xs * yvA[7]);
        acc0 = __builtin_amdgcn_mfma_f32_16x16x32_bf16(
                   wfrag[t], __builtin_bit_cast(short8, u), acc0, 0, 0, 0);

        xs = xvB[t];
        u.x = pack_bf16_2(xs * yvB[0], xs * yvB[1]);
        u.y = pack_bf16_2(xs * yvB[2], xs * yvB[3]);
        u.z = pack_bf16_2(xs * yvB[4], xs * yvB[5]);
        u.w = pack_bf16_2(xs * yvB[6], xs * yvB[7]);
        acc1 = __builtin_amdgcn_mfma_f32_16x16x32_bf16(
                   wfrag[t], __builtin_bit_cast(short8, u), acc1, 0, 0, 0);
    }

    // ---- stores: both 64B halves of each 128B line back-to-back ----
#pragma unroll
    for (int r = 0; r < 4; ++r) {
        const int row = (quad * 4 + r) * FF;
        ob[row + f0]      = acc0[r];
        ob[row + f0 + 16] = acc1[r];
    }
}

extern "C" void kernel_launch(void* const* d_in, const int* in_sizes, int n_in,
                              void* d_out, int out_size, void* d_ws, size_t ws_size,
                              hipStream_t stream) {
    const float* x   = (const float*)d_in[0];
    const float* y   = (const float*)d_in[1];
    const float* cgc = (const float*)d_in[2];
    float* out = (float*)d_out;

    // one block per bm point: 4096 blocks x 256 threads (4 waves)
    hipLaunchKernelGGL(tpc_mfma_lds_kernel, dim3(4096), dim3(256), 0, stream,
                       x, y, cgc, out);
}

// Round 6
// 107.136 us; speedup vs baseline: 1.2912x; 1.0071x over previous
//
#include <hip/hip_runtime.h>
#include <hip/hip_bf16.h>

// out[b,m,d,f] = sum_{a,c} x[b,m,a,f] * y[b,m,c,f] * cgc[a,d,c]
// MFMA per bm: out[16,128] = W[16,256] . P[256,128], k=a*16+c,
//   W[d,k]=cgc[a,d,c] (register A-frags, layout verified R3-R5, absmax 0.25)
//   P[k,f]=x[a,f]*y[c,f] packed to bf16 on the fly.
//
// Round 6 vs round 5 (per-block serial stage->barrier->compute->exit, W-frags
// rebuilt per block, 4096 tiny blocks):
//  - 1024 blocks x 256 threads, each block owns 4 consecutive bm
//  - double-buffered LDS (2 x 16KB): stage(i+1) issued after barrier, compute(i)
//    covers its latency, barrier drains before use
//  - W-frags built once per block (amortized 4x), overlapping stage(0)
//  - 1024 blocks = exactly 4/CU co-resident: no block churn

typedef __attribute__((ext_vector_type(8))) short  short8;
typedef __attribute__((ext_vector_type(4))) float  floatx4;
typedef __attribute__((ext_vector_type(4))) unsigned int uintx4;

#define AA 16
#define FF 128
#define BM_PER_BLOCK 4

static __device__ __forceinline__ unsigned int pack_bf16_2(float lo, float hi) {
    __hip_bfloat162 h = __float22bfloat162_rn(make_float2(lo, hi));  // v_cvt_pk_bf16_f32
    unsigned int u;
    __builtin_memcpy(&u, &h, 4);
    return u;
}

static __device__ __forceinline__ void gload_lds16(const float* g, float* l) {
    __builtin_amdgcn_global_load_lds(
        (const __attribute__((address_space(1))) void*)g,
        (__attribute__((address_space(3))) void*)l,
        16, 0, 0);
}

__global__ __launch_bounds__(256, 4)
void tpc_mfma_pipe_kernel(const float* __restrict__ x,
                          const float* __restrict__ y,
                          const float* __restrict__ cgc,
                          float* __restrict__ out) {
    __shared__ float lx[2][AA * FF];   // 2 x 8KB
    __shared__ float ly[2][AA * FF];   // 2 x 8KB

    const int tid  = threadIdx.x;
    const int w    = tid >> 6;         // wave 0..3
    const int lane = tid & 63;
    const int L    = lane & 15;        // A: m(=d); B: n(=f in tile); D: col
    const int quad = lane >> 4;
    const int qh   = quad >> 1;        // a parity
    const int c0   = (quad & 1) * 8;   // c sub-range

    const int bm0 = blockIdx.x * BM_PER_BLOCK;
    const size_t stride = (size_t)(AA * FF);
    const int off = w * 512 + lane * 4;          // this thread's staging slot

    // ---- stage bm0 -> buf0 (async), then W-frag setup overlaps its latency ----
    {
        const float* xb = x + (size_t)bm0 * stride;
        const float* yb = y + (size_t)bm0 * stride;
        gload_lds16(xb + off,       &lx[0][off]);
        gload_lds16(xb + off + 256, &lx[0][off + 256]);
        gload_lds16(yb + off,       &ly[0][off]);
        gload_lds16(yb + off + 256, &ly[0][off + 256]);
    }

    // ---- A fragments (W) from cgc: once per block ----
    short8 wfrag[8];
#pragma unroll
    for (int t = 0; t < 8; ++t) {
        const float* wp = cgc + (2 * t + qh) * (AA * AA) + L * AA + c0;
        const floatx4 w0 = *(const floatx4*)(wp);
        const floatx4 w1 = *(const floatx4*)(wp + 4);
        uintx4 u;
        u.x = pack_bf16_2(w0.x, w0.y);
        u.y = pack_bf16_2(w0.z, w0.w);
        u.z = pack_bf16_2(w1.x, w1.y);
        u.w = pack_bf16_2(w1.z, w1.w);
        wfrag[t] = __builtin_bit_cast(short8, u);
    }

    __syncthreads();   // buf0 staged

    const int f0 = w * 32 + L;     // wave w owns f-tiles 2w, 2w+1

#pragma unroll
    for (int i = 0; i < BM_PER_BLOCK; ++i) {
        const int cur = i & 1;

        // prefetch next bm into the other buffer; compute below covers latency
        if (i + 1 < BM_PER_BLOCK) {
            const int nxt = (i + 1) & 1;
            const float* xb = x + (size_t)(bm0 + i + 1) * stride;
            const float* yb = y + (size_t)(bm0 + i + 1) * stride;
            gload_lds16(xb + off,       &lx[nxt][off]);
            gload_lds16(xb + off + 256, &lx[nxt][off + 256]);
            gload_lds16(yb + off,       &ly[nxt][off]);
            gload_lds16(yb + off + 256, &ly[nxt][off + 256]);
        }

        // ---- compute bm0+i from buf cur ----
        const float* lxc = lx[cur];
        const float* lyc = ly[cur];

        float xvA[8], xvB[8], yvA[8], yvB[8];
#pragma unroll
        for (int j = 0; j < 8; ++j) {
            yvA[j] = lyc[(c0 + j) * FF + f0];
            yvB[j] = lyc[(c0 + j) * FF + f0 + 16];
        }
#pragma unroll
        for (int t = 0; t < 8; ++t) {
            xvA[t] = lxc[(2 * t + qh) * FF + f0];
            xvB[t] = lxc[(2 * t + qh) * FF + f0 + 16];
        }

        floatx4 acc0 = {0.f, 0.f, 0.f, 0.f};
        floatx4 acc1 = {0.f, 0.f, 0.f, 0.f};
#pragma unroll
        for (int t = 0; t < 8; ++t) {
            uintx4 u;
            float xs = xvA[t];
            u.x = pack_bf16_2(xs * yvA[0], xs * yvA[1]);
            u.y = pack_bf16_2(xs * yvA[2], xs * yvA[3]);
            u.z = pack_bf16_2(xs * yvA[4], xs * yvA[5]);
            u.w = pack_bf16_2(xs * yvA[6], xs * yvA[7]);
            acc0 = __builtin_amdgcn_mfma_f32_16x16x32_bf16(
                       wfrag[t], __builtin_bit_cast(short8, u), acc0, 0, 0, 0);

            xs = xvB[t];
            u.x = pack_bf16_2(xs * yvB[0], xs * yvB[1]);
            u.y = pack_bf16_2(xs * yvB[2], xs * yvB[3]);
            u.z = pack_bf16_2(xs * yvB[4], xs * yvB[5]);
            u.w = pack_bf16_2(xs * yvB[6], xs * yvB[7]);
            acc1 = __builtin_amdgcn_mfma_f32_16x16x32_bf16(
                       wfrag[t], __builtin_bit_cast(short8, u), acc1, 0, 0, 0);
        }

        // ---- stores: both 64B halves of each 128B line back-to-back ----
        float* ob = out + (size_t)(bm0 + i) * stride;
#pragma unroll
        for (int r = 0; r < 4; ++r) {
            const int row = (quad * 4 + r) * FF;
            ob[row + f0]      = acc0[r];
            ob[row + f0 + 16] = acc1[r];
        }

        __syncthreads();   // drains prefetch before next compute; protects buffers
    }
}

extern "C" void kernel_launch(void* const* d_in, const int* in_sizes, int n_in,
                              void* d_out, int out_size, void* d_ws, size_t ws_size,
                              hipStream_t stream) {
    const float* x   = (const float*)d_in[0];
    const float* y   = (const float*)d_in[1];
    const float* cgc = (const float*)d_in[2];
    float* out = (float*)d_out;

    // 4096 bm / 4 per block = 1024 blocks x 256 threads (exactly 4 blocks/CU)
    hipLaunchKernelGGL(tpc_mfma_pipe_kernel, dim3(1024), dim3(256), 0, stream,
                       x, y, cgc, out);
}